// Round 3
// baseline (871.641 us; speedup 1.0000x reference)
//
#include <hip/hip_runtime.h>
#include <math.h>

// Problem constants
#define GS   29
#define GS2  841
#define NCP  24389            // 29^3 control points
#define DW   15
#define PP   225              // DW^2 displacements
#define CH   675              // PP*3 channels per control point
#define CC   8                // feature channels
#define VV   64               // volume side
#define V3   262144           // 64^3

typedef __attribute__((ext_vector_type(8)))  _Float16 half8;

__device__ __forceinline__ float sv(int i) {
    // DR * ((2i+1)/DW - 1)
    return 0.4f * ((2.f * i + 1.f) * (1.f / 15.f) - 1.f);
}

// feat50 (C,D,H,W) fp32 -> two fp16 channel-last volumes:
//   volA: (z,y,x,c)  x fastest   for k=0,1 (lane sweep = x)
//   volB: (z,x,y,c)  y fastest   for k=2   (lane sweep = y)
__global__ __launch_bounds__(256) void make_vols(const float* __restrict__ in,
                                                 _Float16* __restrict__ volA,
                                                 _Float16* __restrict__ volB) {
    int v = blockIdx.x * 256 + threadIdx.x;
    if (v >= V3) return;
    int z = v >> 12, y = (v >> 6) & 63, x = v & 63;
    half8 h;
#pragma unroll
    for (int c = 0; c < CC; c++) h[c] = (_Float16)in[c * V3 + v];
    *(half8*)(volA + (size_t)v * 8) = h;
    *(half8*)(volB + (size_t)((((z << 6) | x) << 6) | y) * 8) = h;
}

// One block per control point n. 704 threads: tid<675 -> (k=tid/225, p=tid%225).
// Computes pdd row (k-major, contiguous 2700B) AND the first min3x3->avg3x3 pool
// (over the 15x15 p-plane per k) in LDS. Packed-fp16 sampling math.
__global__ __launch_bounds__(704) void pdd_pool(const float* __restrict__ f00,
                                                const _Float16* __restrict__ volA,
                                                const _Float16* __restrict__ volB,
                                                const float* __restrict__ grid,
                                                const float* __restrict__ alpha,
                                                float* __restrict__ pdd,   // (n, k*225+p)
                                                float* __restrict__ pool) {// (n, k*225+p)
    int n = blockIdx.x;
    int tid = threadIdx.x;
    __shared__ __align__(16) _Float16 fixh[8];
    __shared__ float svals[CH];
    __shared__ float smin[3 * 17 * 17];

    float gx = grid[n * 3 + 0], gy = grid[n * 3 + 1], gz = grid[n * 3 + 2];

    if (tid < 8) {
        // trilerp feat00 channel tid at grid point, padding_mode='zeros' (fp32)
        float ix = 0.5f * ((gx + 1.f) * VV - 1.f);
        float iy = 0.5f * ((gy + 1.f) * VV - 1.f);
        float iz = 0.5f * ((gz + 1.f) * VV - 1.f);
        float x0f = floorf(ix), y0f = floorf(iy), z0f = floorf(iz);
        float fx = ix - x0f, fy = iy - y0f, fz = iz - z0f;
        int x0 = (int)x0f, y0 = (int)y0f, z0 = (int)z0f;
        const float* fc = f00 + tid * V3;
        float acc = 0.f;
        for (int dz = 0; dz < 2; dz++) {
            int zi = z0 + dz; float wz = dz ? fz : 1.f - fz;
            for (int dy = 0; dy < 2; dy++) {
                int yi = y0 + dy; float wy = dy ? fy : 1.f - fy;
                for (int dx = 0; dx < 2; dx++) {
                    int xi = x0 + dx; float wx = dx ? fx : 1.f - fx;
                    if (xi >= 0 && xi < VV && yi >= 0 && yi < VV && zi >= 0 && zi < VV)
                        acc += wx * wy * wz * fc[(zi * VV + yi) * VV + xi];
                }
            }
        }
        fixh[tid] = (_Float16)acc;
    }
    __syncthreads();

    float myval = 0.f;
    if (tid < CH) {
        int k = tid / PP, p = tid - PP * k;
        int h_ = p / 15, w_ = p - 15 * h_;
        float A = sv(h_), B = sv(w_);

        float pu, pv, pw;
        const _Float16* vol;
        if (k == 0)      { pu = gx + B; pv = gy + A; pw = gz;     vol = volA; }
        else if (k == 1) { pu = gx + B; pv = gy;     pw = gz + A; vol = volA; }
        else             { pu = gy + B; pv = gx;     pw = gz + A; vol = volB; }

        float iu = 0.5f * ((pu + 1.f) * VV - 1.f);
        float iv = 0.5f * ((pv + 1.f) * VV - 1.f);
        float iw = 0.5f * ((pw + 1.f) * VV - 1.f);
        float u0f = floorf(iu), v0f = floorf(iv), w0f = floorf(iw);
        float fu = iu - u0f, fv = iv - v0f, fw = iw - w0f;
        int u0 = (int)u0f, v0 = (int)v0f, w0 = (int)w0f;

        // u handled as an adjacent voxel PAIR: one 32B (2x16B) load gets both corners
        int p0 = min(max(u0, 0), VV - 2);
        float wAu = (u0 < 0) ? 1.f : ((u0 >= VV - 1) ? 0.f : (1.f - fu));
        float wBu = 1.f - wAu;
        int v0c = min(max(v0, 0), VV - 1), v1c = min(max(v0 + 1, 0), VV - 1);
        int w0c = min(max(w0, 0), VV - 1), w1c = min(max(w0 + 1, 0), VV - 1);
        float wv0 = 1.f - fv, wv1 = fv;
        float ww0 = 1.f - fw, ww1 = fw;

        half8 acc = {0, 0, 0, 0, 0, 0, 0, 0};
#define PAIR(WC, VC, WGT) {                                               \
            float fA_ = (WGT) * wAu, fB_ = (WGT) * wBu;                   \
            _Float16 hA_ = (_Float16)fA_, hB_ = (_Float16)fB_;            \
            half8 hA8 = {hA_, hA_, hA_, hA_, hA_, hA_, hA_, hA_};         \
            half8 hB8 = {hB_, hB_, hB_, hB_, hB_, hB_, hB_, hB_};         \
            const _Float16* vp = vol + (size_t)((((WC) * VV) + (VC)) * VV + p0) * 8; \
            half8 lo = *(const half8*)vp;                                 \
            half8 hi = *(const half8*)(vp + 8);                           \
            acc += hA8 * lo;                                              \
            acc += hB8 * hi;                                              \
        }
        PAIR(w0c, v0c, ww0 * wv0)
        PAIR(w0c, v1c, ww0 * wv1)
        PAIR(w1c, v0c, ww1 * wv0)
        PAIR(w1c, v1c, ww1 * wv1)
#undef PAIR

        half8 f8 = *(const half8*)fixh;
        half8 d8 = f8 - acc;
        float ssd = 0.f;
#pragma unroll
        for (int c = 0; c < 8; c++) { float dc = (float)d8[c]; ssd = fmaf(dc, dc, ssd); }
        myval = alpha[1] + alpha[0] * ssd;
        svals[tid] = myval;
    }
    __syncthreads();

    // min3x3 over pad-2 edge-clamped 15x15 (per k): 3*17*17 = 867 outputs
    for (int idx = tid; idx < 867; idx += 704) {
        int k = idx / 289; int r = idx - 289 * k; int a = r / 17; int b = r - 17 * a;
        float mn = 1e30f;
        for (int u = 0; u < 3; u++) {
            int hh = min(max(a + u - 2, 0), 14);
            for (int v = 0; v < 3; v++) {
                int ww = min(max(b + v - 2, 0), 14);
                mn = fminf(mn, svals[k * PP + hh * 15 + ww]);
            }
        }
        smin[idx] = mn;
    }
    __syncthreads();
    if (tid < CH) {
        int k = tid / PP, p = tid - PP * k;
        int h = p / 15, w = p - 15 * h;
        float acc = 0.f;
        for (int a = 0; a < 3; a++)
            for (int b = 0; b < 3; b++)
                acc += smin[k * 289 + (h + a) * 17 + (w + b)];
        pool[(size_t)n * CH + tid] = acc * (1.f / 9.f);
        pdd[(size_t)n * CH + tid] = myval;
    }
}

// Fused grid_smooth (5-tap triangle [1,2,3,2,1]/9 along z then y, edge clamp)
// over a full 29x29 (z,y) plane held in LDS for fixed x and a 9-channel chunk.
#define CCH 9
#define NE  (GS2 * CCH)   // 7569

__global__ __launch_bounds__(1024) void gszy_cost(const float* __restrict__ in,
                                                  float* pc,   // pdd in, cost out (in-place)
                                                  const float* __restrict__ alpha) {
    __shared__ float Ax[NE];
    __shared__ float Bx[NE];
    int x = blockIdx.x;
    int c0 = blockIdx.y * CCH;
    int tid = threadIdx.x;
    for (int e = tid; e < NE; e += 1024) {
        int zy = e / CCH; int cc = e - CCH * zy;
        Ax[e] = in[((size_t)zy * GS + x) * CH + c0 + cc];
    }
    __syncthreads();
    const float w0 = 1.f / 9.f, w1 = 2.f / 9.f, w2 = 3.f / 9.f;
    for (int e = tid; e < NE; e += 1024) {
        int zy = e / CCH; int cc = e - CCH * zy;
        int z = zy / GS; int y = zy - GS * z;
        int zm2 = max(z - 2, 0), zm1 = max(z - 1, 0);
        int zp1 = min(z + 1, GS - 1), zp2 = min(z + 2, GS - 1);
        Bx[e] = w0 * Ax[(zm2 * GS + y) * CCH + cc] + w1 * Ax[(zm1 * GS + y) * CCH + cc]
              + w2 * Ax[(z * GS + y) * CCH + cc]
              + w1 * Ax[(zp1 * GS + y) * CCH + cc] + w0 * Ax[(zp2 * GS + y) * CCH + cc];
    }
    __syncthreads();
    float a2 = alpha[2], a3 = alpha[3], a4 = alpha[4];
    for (int e = tid; e < NE; e += 1024) {
        int zy = e / CCH; int cc = e - CCH * zy;
        int z = zy / GS; int y = zy - GS * z;
        int ym2 = max(y - 2, 0), ym1 = max(y - 1, 0);
        int yp1 = min(y + 1, GS - 1), yp2 = min(y + 2, GS - 1);
        float val = w0 * Bx[(z * GS + ym2) * CCH + cc] + w1 * Bx[(z * GS + ym1) * CCH + cc]
                  + w2 * Bx[e]
                  + w1 * Bx[(z * GS + yp1) * CCH + cc] + w0 * Bx[(z * GS + yp2) * CCH + cc];
        size_t g = ((size_t)zy * GS + x) * CH + c0 + cc;
        pc[g] = a4 + a2 * pc[g] + a3 * val;
    }
}

__global__ __launch_bounds__(1024) void gszy_fin(const float* __restrict__ in,
                                                 float* __restrict__ out) {
    __shared__ float Ax[NE];
    __shared__ float Bx[NE];
    int x = blockIdx.x;
    int c0 = blockIdx.y * CCH;
    int tid = threadIdx.x;
    for (int e = tid; e < NE; e += 1024) {
        int zy = e / CCH; int cc = e - CCH * zy;
        Ax[e] = in[((size_t)zy * GS + x) * CH + c0 + cc];
    }
    __syncthreads();
    const float w0 = 1.f / 9.f, w1 = 2.f / 9.f, w2 = 3.f / 9.f;
    for (int e = tid; e < NE; e += 1024) {
        int zy = e / CCH; int cc = e - CCH * zy;
        int z = zy / GS; int y = zy - GS * z;
        int zm2 = max(z - 2, 0), zm1 = max(z - 1, 0);
        int zp1 = min(z + 1, GS - 1), zp2 = min(z + 2, GS - 1);
        Bx[e] = w0 * Ax[(zm2 * GS + y) * CCH + cc] + w1 * Ax[(zm1 * GS + y) * CCH + cc]
              + w2 * Ax[(z * GS + y) * CCH + cc]
              + w1 * Ax[(zp1 * GS + y) * CCH + cc] + w0 * Ax[(zp2 * GS + y) * CCH + cc];
    }
    __syncthreads();
    for (int e = tid; e < NE; e += 1024) {
        int zy = e / CCH; int cc = e - CCH * zy;
        int z = zy / GS; int y = zy - GS * z;
        int ym2 = max(y - 2, 0), ym1 = max(y - 1, 0);
        int yp1 = min(y + 1, GS - 1), yp2 = min(y + 2, GS - 1);
        float val = w0 * Bx[(z * GS + ym2) * CCH + cc] + w1 * Bx[(z * GS + ym1) * CCH + cc]
                  + w2 * Bx[e]
                  + w1 * Bx[(z * GS + yp1) * CCH + cc] + w0 * Bx[(z * GS + yp2) * CCH + cc];
        out[((size_t)zy * GS + x) * CH + c0 + cc] = val;
    }
}

// Second pool: reads cost (k-major), writes pool in ORIGINAL (p*3+k) layout
// (the permute is free: whole row is LDS-resident, block writes full row)
__global__ __launch_bounds__(704) void pool2(const float* __restrict__ in,
                                             float* __restrict__ out) {
    int n = blockIdx.x;
    int tid = threadIdx.x;
    __shared__ float svals[CH];
    __shared__ float smin[3 * 17 * 17];
    for (int i = tid; i < CH; i += 704) svals[i] = in[(size_t)n * CH + i];
    __syncthreads();
    for (int idx = tid; idx < 867; idx += 704) {
        int k = idx / 289; int r = idx - 289 * k; int a = r / 17; int b = r - 17 * a;
        float mn = 1e30f;
        for (int u = 0; u < 3; u++) {
            int hh = min(max(a + u - 2, 0), 14);
            for (int v = 0; v < 3; v++) {
                int ww = min(max(b + v - 2, 0), 14);
                mn = fminf(mn, svals[k * PP + hh * 15 + ww]);
            }
        }
        smin[idx] = mn;
    }
    __syncthreads();
    if (tid < CH) {
        int k = tid / PP, p = tid - PP * k;
        int h = p / 15, w = p - 15 * h;
        float acc = 0.f;
        for (int a = 0; a < 3; a++)
            for (int b = 0; b < 3; b++)
                acc += smin[k * 289 + (h + a) * 17 + (w + b)];
        out[(size_t)n * CH + 3 * p + k] = acc * (1.f / 9.f);   // layout permute here
    }
}

// softmax over p (per n,k) + pred_xyz einsum — wave-shuffle reductions
// input/output rows are in original (p*3+k) layout
__global__ __launch_bounds__(256) void softmax_pred2(const float* __restrict__ ca,
                                                     const float* __restrict__ alpha,
                                                     float* __restrict__ soft,
                                                     float* __restrict__ pred) {
    int n = blockIdx.x;
    int tid = threadIdx.x;
    int wave = tid >> 6, lane = tid & 63;
    __shared__ float vals[CH];
    __shared__ float partial[3][3];
    for (int i = tid; i < CH; i += 256) vals[i] = ca[(size_t)n * CH + i];
    __syncthreads();
    float a5 = alpha[5];
    if (wave < 3) {
        int k = wave;
        float v[4], e[4];
        float m = -1e30f;
#pragma unroll
        for (int j = 0; j < 4; j++) {
            int p = lane + 64 * j;
            v[j] = (p < PP) ? -a5 * vals[p * 3 + k] : -1e30f;
            m = fmaxf(m, v[j]);
        }
#pragma unroll
        for (int o = 32; o > 0; o >>= 1) m = fmaxf(m, __shfl_xor(m, o));
        float sum = 0.f;
#pragma unroll
        for (int j = 0; j < 4; j++) {
            int p = lane + 64 * j;
            e[j] = (p < PP) ? __expf(v[j] - m) : 0.f;
            sum += e[j];
        }
#pragma unroll
        for (int o = 32; o > 0; o >>= 1) sum += __shfl_xor(sum, o);
        float inv = 1.f / sum;
        float px = 0.f, py = 0.f, pz = 0.f;
#pragma unroll
        for (int j = 0; j < 4; j++) {
            int p = lane + 64 * j;
            if (p < PP) {
                float s = e[j] * inv;
                vals[p * 3 + k] = s;
                int h_ = p / 15, w_ = p - 15 * h_;
                float A = sv(h_), B = sv(w_);
                if (k == 0)      { px += s * B; py += s * A; }
                else if (k == 1) { px += s * B; pz += s * A; }
                else             { py += s * B; pz += s * A; }
            }
        }
#pragma unroll
        for (int o = 32; o > 0; o >>= 1) {
            px += __shfl_xor(px, o);
            py += __shfl_xor(py, o);
            pz += __shfl_xor(pz, o);
        }
        if (lane == 0) { partial[k][0] = px; partial[k][1] = py; partial[k][2] = pz; }
    }
    __syncthreads();
    if (tid < 3) pred[(size_t)n * 3 + tid] = 0.5f * (partial[0][tid] + partial[1][tid] + partial[2][tid]);
    for (int i = tid; i < CH; i += 256) soft[(size_t)n * CH + i] = vals[i];
}

extern "C" void kernel_launch(void* const* d_in, const int* in_sizes, int n_in,
                              void* d_out, int out_size, void* d_ws, size_t ws_size,
                              hipStream_t stream) {
    const float* f00   = (const float*)d_in[0];
    const float* f50   = (const float*)d_in[1];
    // d_in[2] (shift_2d_min) broadcast of shift_2d -- unused
    const float* grid  = (const float*)d_in[3];
    // d_in[4] (shift_2d) recomputed analytically -- unused
    const float* alpha = (const float*)d_in[5];

    float* out0 = (float*)d_out;                   // cost_soft  (N*675)
    float* out1 = out0 + (size_t)NCP * CH;         // pred_xyz   (N*3)
    float* out2 = out1 + (size_t)NCP * 3;          // cost_avg   (N*675)

    char* ws = (char*)d_ws;
    _Float16* volA = (_Float16*)ws;                          // 4MB
    _Float16* volB = volA + (size_t)V3 * 8;                  // 4MB
    float* W0 = (float*)(volB + (size_t)V3 * 8);             // N*CH
    float* W1 = W0 + (size_t)NCP * CH;                       // N*CH

    make_vols<<<(V3 + 255) / 256, 256, 0, stream>>>(f50, volA, volB);

    // K2: pdd + first pool fused (k-major rows)
    pdd_pool<<<NCP, 704, 0, stream>>>(f00, volA, volB, grid, alpha, W0, W1);

    // K3: fused grid_smooth(z+y) + affine combine (in-place on W0)
    gszy_cost<<<dim3(GS, CH / CCH), 1024, 0, stream>>>(W1, W0, alpha);

    // K4: second pool, permutes k-major -> (p*3+k) layout
    pool2<<<NCP, 704, 0, stream>>>(W0, W1);

    // K5: fused grid_smooth(z+y) -> cost_avg (original layout)
    gszy_fin<<<dim3(GS, CH / CCH), 1024, 0, stream>>>(W1, out2);

    // K6: softmax + pred
    softmax_pred2<<<NCP, 256, 0, stream>>>(out2, alpha, out0, out1);
}

// Round 5
// 558.484 us; speedup vs baseline: 1.5607x; 1.5607x over previous
//
#include <hip/hip_runtime.h>
#include <math.h>

// Problem constants
#define GS   29
#define GS2  841
#define NCP  24389            // 29^3 control points
#define DW   15
#define PP   225              // DW^2 displacements
#define CH   675              // PP*3 channels per control point
#define CC   8                // feature channels
#define VV   64               // volume side
#define V3   262144           // 64^3

typedef __attribute__((ext_vector_type(8))) _Float16 half8;

__device__ __forceinline__ float sv(int i) {
    // DR * ((2i+1)/DW - 1)
    return 0.4f * ((2.f * i + 1.f) * (1.f / 15.f) - 1.f);
}

// feat50 (C,D,H,W) fp32 -> two fp16 channel-last volumes:
//   volA: (z,y,x,c)  x fastest   for k=0,1 (lane sweep = x)
//   volB: (z,x,y,c)  y fastest   for k=2   (lane sweep = y)
__global__ __launch_bounds__(256) void make_vols(const float* __restrict__ in,
                                                 _Float16* __restrict__ volA,
                                                 _Float16* __restrict__ volB) {
    int v = blockIdx.x * 256 + threadIdx.x;
    if (v >= V3) return;
    int z = v >> 12, y = (v >> 6) & 63, x = v & 63;
    half8 h;
#pragma unroll
    for (int c = 0; c < CC; c++) h[c] = (_Float16)in[c * V3 + v];
    *(half8*)(volA + (size_t)v * 8) = h;
    *(half8*)(volB + (size_t)((((z << 6) | x) << 6) | y) * 8) = h;
}

// Block per n, 256 threads. Lane p (<225) samples all 3 planes (PAIR fp16 math),
// builds the ORIGINAL-layout (p*3+k) pdd row in LDS, fuses the first
// min3x3->avg3x3 pool, writes both rows contiguously as fp16.
__global__ __launch_bounds__(256) void pdd_pool_n(const float* __restrict__ f00,
                                                  const _Float16* __restrict__ volA,
                                                  const _Float16* __restrict__ volB,
                                                  const float* __restrict__ grid,
                                                  const float* __restrict__ alpha,
                                                  _Float16* __restrict__ pdd,    // (n, p*3+k)
                                                  _Float16* __restrict__ pool) { // (n, p*3+k)
    int n = blockIdx.x;
    int tid = threadIdx.x;
    __shared__ __align__(16) _Float16 fixh[8];
    __shared__ float rowp[CH];
    __shared__ float smin[3 * 289];

    float gx = grid[n * 3 + 0], gy = grid[n * 3 + 1], gz = grid[n * 3 + 2];

    if (tid < 8) {
        // trilerp feat00 channel tid at grid point, padding_mode='zeros' (fp32)
        float ix = 0.5f * ((gx + 1.f) * VV - 1.f);
        float iy = 0.5f * ((gy + 1.f) * VV - 1.f);
        float iz = 0.5f * ((gz + 1.f) * VV - 1.f);
        float x0f = floorf(ix), y0f = floorf(iy), z0f = floorf(iz);
        float fx = ix - x0f, fy = iy - y0f, fz = iz - z0f;
        int x0 = (int)x0f, y0 = (int)y0f, z0 = (int)z0f;
        const float* fc = f00 + tid * V3;
        float acc = 0.f;
        for (int dz = 0; dz < 2; dz++) {
            int zi = z0 + dz; float wz = dz ? fz : 1.f - fz;
            for (int dy = 0; dy < 2; dy++) {
                int yi = y0 + dy; float wy = dy ? fy : 1.f - fy;
                for (int dx = 0; dx < 2; dx++) {
                    int xi = x0 + dx; float wx = dx ? fx : 1.f - fx;
                    if (xi >= 0 && xi < VV && yi >= 0 && yi < VV && zi >= 0 && zi < VV)
                        acc += wx * wy * wz * fc[(zi * VV + yi) * VV + xi];
                }
            }
        }
        fixh[tid] = (_Float16)acc;
    }
    __syncthreads();

    if (tid < PP) {
        int p = tid;
        int h_ = p / 15, w_ = p - 15 * h_;
        float A = sv(h_), B = sv(w_);
        half8 f8 = *(const half8*)fixh;
        float a0 = alpha[0], a1 = alpha[1];

        for (int k = 0; k < 3; k++) {
            float pu, pv, pw;
            const _Float16* vol;
            if (k == 0)      { pu = gx + B; pv = gy + A; pw = gz;     vol = volA; }
            else if (k == 1) { pu = gx + B; pv = gy;     pw = gz + A; vol = volA; }
            else             { pu = gy + B; pv = gx;     pw = gz + A; vol = volB; }

            float iu = 0.5f * ((pu + 1.f) * VV - 1.f);
            float iv = 0.5f * ((pv + 1.f) * VV - 1.f);
            float iw = 0.5f * ((pw + 1.f) * VV - 1.f);
            float u0f = floorf(iu), v0f = floorf(iv), w0f = floorf(iw);
            float fu = iu - u0f, fv = iv - v0f, fw = iw - w0f;
            int u0 = (int)u0f, v0 = (int)v0f, w0 = (int)w0f;

            // u as adjacent voxel PAIR: one 32B load pair gets both u-corners
            int p0 = min(max(u0, 0), VV - 2);
            float wAu = (u0 < 0) ? 1.f : ((u0 >= VV - 1) ? 0.f : (1.f - fu));
            float wBu = 1.f - wAu;
            int v0c = min(max(v0, 0), VV - 1), v1c = min(max(v0 + 1, 0), VV - 1);
            int w0c = min(max(w0, 0), VV - 1), w1c = min(max(w0 + 1, 0), VV - 1);
            float wv0 = 1.f - fv, wv1 = fv;
            float ww0 = 1.f - fw, ww1 = fw;

            half8 acc = {0, 0, 0, 0, 0, 0, 0, 0};
#define PAIR(WC, VC, WGT) {                                               \
                float fA_ = (WGT) * wAu, fB_ = (WGT) * wBu;               \
                _Float16 hA_ = (_Float16)fA_, hB_ = (_Float16)fB_;        \
                half8 hA8 = {hA_, hA_, hA_, hA_, hA_, hA_, hA_, hA_};     \
                half8 hB8 = {hB_, hB_, hB_, hB_, hB_, hB_, hB_, hB_};     \
                const _Float16* vp = vol + (size_t)((((WC) * VV) + (VC)) * VV + p0) * 8; \
                half8 lo = *(const half8*)vp;                             \
                half8 hi = *(const half8*)(vp + 8);                       \
                acc += hA8 * lo;                                          \
                acc += hB8 * hi;                                          \
            }
            PAIR(w0c, v0c, ww0 * wv0)
            PAIR(w0c, v1c, ww0 * wv1)
            PAIR(w1c, v0c, ww1 * wv0)
            PAIR(w1c, v1c, ww1 * wv1)
#undef PAIR

            half8 d8 = f8 - acc;
            float ssd = 0.f;
#pragma unroll
            for (int c = 0; c < 8; c++) { float dc = (float)d8[c]; ssd = fmaf(dc, dc, ssd); }
            rowp[p * 3 + k] = a1 + a0 * ssd;
        }
    }
    __syncthreads();

    // min3x3 over pad-2 edge-clamped 15x15, per k: 3*17*17 = 867 outputs
    for (int idx = tid; idx < 867; idx += 256) {
        int k = idx / 289; int r = idx - 289 * k; int a = r / 17; int b = r - 17 * a;
        float mn = 1e30f;
        for (int u = 0; u < 3; u++) {
            int hh = min(max(a + u - 2, 0), 14);
            for (int v = 0; v < 3; v++) {
                int ww = min(max(b + v - 2, 0), 14);
                mn = fminf(mn, rowp[(hh * 15 + ww) * 3 + k]);
            }
        }
        smin[idx] = mn;
    }
    __syncthreads();

    for (int i = tid; i < CH; i += 256) {
        pdd[(size_t)n * CH + i] = (_Float16)rowp[i];
        int p = i / 3, k = i - 3 * p;              // i = p*3+k
        int h = p / 15, w = p - 15 * h;
        float acc = 0.f;
        for (int a = 0; a < 3; a++)
            for (int b = 0; b < 3; b++)
                acc += smin[k * 289 + (h + a) * 17 + (w + b)];
        pool[(size_t)n * CH + i] = (_Float16)(acc * (1.f / 9.f));
    }
}

// 5-tap triangle [1,2,3,2,1]/9 along z, sliding window (fp16 in/out).
__global__ __launch_bounds__(256) void gs_z2_h(const _Float16* __restrict__ in,
                                               _Float16* __restrict__ out) {
    const int ZS = GS2 * CH;
    int id = blockIdx.x * 256 + threadIdx.x;
    if (id >= ZS) return;
    const float w0 = 1.f / 9.f, w1 = 2.f / 9.f, w2 = 3.f / 9.f;
    const _Float16* p = in + id;
    float v0 = (float)p[0], v1 = v0, v2 = v0;
    float v3 = (float)p[ZS], v4 = (float)p[2 * (size_t)ZS];
    for (int z = 0; z < GS; z++) {
        out[id + (size_t)z * ZS] = (_Float16)(w0 * v0 + w1 * v1 + w2 * v2 + w1 * v3 + w0 * v4);
        v0 = v1; v1 = v2; v2 = v3; v3 = v4;
        int zn = z + 3; if (zn > GS - 1) zn = GS - 1;
        v4 = (float)p[(size_t)zn * ZS];
    }
}

// y-pass fused with cost = a4 + a2*pdd + a3*gs (in-place on pc, fp16).
__global__ __launch_bounds__(256) void gs_y_cost2_h(const _Float16* __restrict__ zt,
                                                    _Float16* pc,
                                                    const float* __restrict__ alpha) {
    const int ZS = GS2 * CH, YS = GS * CH;
    int id = blockIdx.x * 256 + threadIdx.x;
    if (id >= GS * YS) return;
    int z = id / YS; int rem = id - z * YS;        // rem = x*CH + c
    size_t base = (size_t)z * ZS + rem;
    const float w0 = 1.f / 9.f, w1 = 2.f / 9.f, w2 = 3.f / 9.f;
    float a2 = alpha[2], a3 = alpha[3], a4 = alpha[4];
    const _Float16* p = zt + base;
    float v0 = (float)p[0], v1 = v0, v2 = v0;
    float v3 = (float)p[YS], v4 = (float)p[2 * (size_t)YS];
    for (int y = 0; y < GS; y++) {
        size_t idx = base + (size_t)y * YS;
        float acc = w0 * v0 + w1 * v1 + w2 * v2 + w1 * v3 + w0 * v4;
        float cur = (float)pc[idx];
        pc[idx] = (_Float16)(a4 + a2 * cur + a3 * acc);
        v0 = v1; v1 = v2; v2 = v3; v3 = v4;
        int yn = y + 3; if (yn > GS - 1) yn = GS - 1;
        v4 = (float)p[(size_t)yn * YS];
    }
}

// plain y-pass: fp16 in -> fp32 out (final grid_smooth -> cost_avg, original layout)
__global__ __launch_bounds__(256) void gs_y2_hf(const _Float16* __restrict__ zt,
                                                float* __restrict__ out) {
    const int ZS = GS2 * CH, YS = GS * CH;
    int id = blockIdx.x * 256 + threadIdx.x;
    if (id >= GS * YS) return;
    int z = id / YS; int rem = id - z * YS;
    size_t base = (size_t)z * ZS + rem;
    const float w0 = 1.f / 9.f, w1 = 2.f / 9.f, w2 = 3.f / 9.f;
    const _Float16* p = zt + base;
    float v0 = (float)p[0], v1 = v0, v2 = v0;
    float v3 = (float)p[YS], v4 = (float)p[2 * (size_t)YS];
    for (int y = 0; y < GS; y++) {
        out[base + (size_t)y * YS] = w0 * v0 + w1 * v1 + w2 * v2 + w1 * v3 + w0 * v4;
        v0 = v1; v1 = v2; v2 = v3; v3 = v4;
        int yn = y + 3; if (yn > GS - 1) yn = GS - 1;
        v4 = (float)p[(size_t)yn * YS];
    }
}

// Second pool (original layout, fp16 in/out) — structure verbatim from R2-passing pool_kernel.
__global__ __launch_bounds__(256) void pool_h(const _Float16* __restrict__ in,
                                              _Float16* __restrict__ out) {
    int n = blockIdx.x;
    int tid = threadIdx.x;
    __shared__ float sin_[CH];
    __shared__ float smn[17 * 17 * 3];
    for (int i = tid; i < CH; i += 256) sin_[i] = (float)in[(size_t)n * CH + i];
    __syncthreads();
    for (int idx = tid; idx < 17 * 17 * 3; idx += 256) {
        int a = idx / 51; int r = idx - 51 * a; int b = r / 3; int k = r - 3 * b;
        float mn = 1e30f;
        for (int u = 0; u < 3; u++) {
            int hh = min(max(a + u - 2, 0), 14);
            for (int v = 0; v < 3; v++) {
                int ww = min(max(b + v - 2, 0), 14);
                mn = fminf(mn, sin_[(hh * 15 + ww) * 3 + k]);
            }
        }
        smn[idx] = mn;
    }
    __syncthreads();
    for (int s = tid; s < CH; s += 256) {
        int h = s / 45; int r = s - 45 * h; int w = r / 3; int k = r - 3 * w;
        float acc = 0.f;
        for (int a = 0; a < 3; a++)
            for (int b = 0; b < 3; b++)
                acc += smn[(h + a) * 51 + (w + b) * 3 + k];
        out[(size_t)n * CH + s] = (_Float16)(acc * (1.f / 9.f));
    }
}

// softmax over p (per n,k) + pred_xyz einsum — verbatim from R2-passing kernel.
__global__ __launch_bounds__(256) void softmax_pred2(const float* __restrict__ ca,
                                                     const float* __restrict__ alpha,
                                                     float* __restrict__ soft,
                                                     float* __restrict__ pred) {
    int n = blockIdx.x;
    int tid = threadIdx.x;
    int wave = tid >> 6, lane = tid & 63;
    __shared__ float vals[CH];
    __shared__ float partial[3][3];
    for (int i = tid; i < CH; i += 256) vals[i] = ca[(size_t)n * CH + i];
    __syncthreads();
    float a5 = alpha[5];
    if (wave < 3) {
        int k = wave;
        float v[4], e[4];
        float m = -1e30f;
#pragma unroll
        for (int j = 0; j < 4; j++) {
            int p = lane + 64 * j;
            v[j] = (p < PP) ? -a5 * vals[p * 3 + k] : -1e30f;
            m = fmaxf(m, v[j]);
        }
#pragma unroll
        for (int o = 32; o > 0; o >>= 1) m = fmaxf(m, __shfl_xor(m, o));
        float sum = 0.f;
#pragma unroll
        for (int j = 0; j < 4; j++) {
            int p = lane + 64 * j;
            e[j] = (p < PP) ? __expf(v[j] - m) : 0.f;
            sum += e[j];
        }
#pragma unroll
        for (int o = 32; o > 0; o >>= 1) sum += __shfl_xor(sum, o);
        float inv = 1.f / sum;
        float px = 0.f, py = 0.f, pz = 0.f;
#pragma unroll
        for (int j = 0; j < 4; j++) {
            int p = lane + 64 * j;
            if (p < PP) {
                float s = e[j] * inv;
                vals[p * 3 + k] = s;
                int h_ = p / 15, w_ = p - 15 * h_;
                float A = sv(h_), B = sv(w_);
                if (k == 0)      { px += s * B; py += s * A; }
                else if (k == 1) { px += s * B; pz += s * A; }
                else             { py += s * B; pz += s * A; }
            }
        }
#pragma unroll
        for (int o = 32; o > 0; o >>= 1) {
            px += __shfl_xor(px, o);
            py += __shfl_xor(py, o);
            pz += __shfl_xor(pz, o);
        }
        if (lane == 0) { partial[k][0] = px; partial[k][1] = py; partial[k][2] = pz; }
    }
    __syncthreads();
    if (tid < 3) pred[(size_t)n * 3 + tid] = 0.5f * (partial[0][tid] + partial[1][tid] + partial[2][tid]);
    for (int i = tid; i < CH; i += 256) soft[(size_t)n * CH + i] = vals[i];
}

extern "C" void kernel_launch(void* const* d_in, const int* in_sizes, int n_in,
                              void* d_out, int out_size, void* d_ws, size_t ws_size,
                              hipStream_t stream) {
    const float* f00   = (const float*)d_in[0];
    const float* f50   = (const float*)d_in[1];
    // d_in[2] (shift_2d_min) broadcast of shift_2d -- unused
    const float* grid  = (const float*)d_in[3];
    // d_in[4] (shift_2d) recomputed analytically -- unused
    const float* alpha = (const float*)d_in[5];

    float* out0 = (float*)d_out;                   // cost_soft  (N*675)
    float* out1 = out0 + (size_t)NCP * CH;         // pred_xyz   (N*3)
    float* out2 = out1 + (size_t)NCP * 3;          // cost_avg   (N*675)

    char* ws = (char*)d_ws;
    _Float16* volA = (_Float16*)ws;                          // 4MB
    _Float16* volB = volA + (size_t)V3 * 8;                  // 4MB
    _Float16* H0 = volB + (size_t)V3 * 8;                    // N*CH fp16 (pdd -> cost)
    _Float16* H1 = H0 + (size_t)NCP * CH;                    // N*CH fp16
    _Float16* H2 = H1 + (size_t)NCP * CH;                    // N*CH fp16

    make_vols<<<(V3 + 255) / 256, 256, 0, stream>>>(f50, volA, volB);

    // pdd + pool1 fused, ORIGINAL (p*3+k) layout rows, contiguous fp16 writes
    pdd_pool_n<<<NCP, 256, 0, stream>>>(f00, volA, volB, grid, alpha, H0, H1);

    const int TOT = GS2 * CH;
    const int gb2 = (TOT + 255) / 256;

    gs_z2_h<<<gb2, 256, 0, stream>>>(H1, H2);
    gs_y_cost2_h<<<gb2, 256, 0, stream>>>(H2, H0, alpha);   // cost in H0

    pool_h<<<NCP, 256, 0, stream>>>(H0, H1);
    gs_z2_h<<<gb2, 256, 0, stream>>>(H1, H2);
    gs_y2_hf<<<gb2, 256, 0, stream>>>(H2, out2);            // fp32 cost_avg

    softmax_pred2<<<NCP, 256, 0, stream>>>(out2, alpha, out0, out1);
}